// Round 6
// baseline (1796.620 us; speedup 1.0000x reference)
//
#include <hip/hip_runtime.h>
#include <hip/hip_cooperative_groups.h>

namespace cg = cooperative_groups;

// D = H = W = 128, NUM_STEPS = 7 (MONAI DVF2DDF scaling-and-squaring)
#define DD 128
constexpr int NV = DD * DD * DD;          // 2,097,152 voxels
constexpr float INV_SCALE = 1.0f / 128.0f; // 2^-NUM_STEPS
#define NXCD 8

__device__ __forceinline__ int swz(int b, int cpx) {
    return (b & (NXCD - 1)) * cpx + (b >> 3);
}

__device__ __forceinline__ void unpack_zyx(int tid, int& z, int& y, int& x) {
    x = tid & (DD - 1);
    y = (tid >> 7) & (DD - 1);
    z = tid >> 14;
}

__device__ __forceinline__ float clampd(float v) {
    return fminf(fmaxf(v, 0.0f), (float)(DD - 1));
}

// ---------------------------------------------------------------------------
// trilinear sample of interleaved 3-channel field (EXACT round-0 expression
// order — verified bit-stable, absmax 0.00390625)
// ---------------------------------------------------------------------------
__device__ __forceinline__ void trilerp3(const float* __restrict__ src,
                                         float cz, float cy, float cx,
                                         float& r0, float& r1, float& r2) {
    float z0f = floorf(cz), y0f = floorf(cy), x0f = floorf(cx);
    float wz = cz - z0f, wy = cy - y0f, wx = cx - x0f;
    int z0 = (int)z0f, y0 = (int)y0f, x0 = (int)x0f;
    int z1 = min(z0 + 1, DD - 1);
    int y1 = min(y0 + 1, DD - 1);
    int x1 = min(x0 + 1, DD - 1);
    float omz = 1.0f - wz, omy = 1.0f - wy, omx = 1.0f - wx;

    int zs0 = z0 << 14, zs1 = z1 << 14;
    int ys0 = y0 << 7,  ys1 = y1 << 7;

    const float* p000 = src + 3 * (zs0 + ys0 + x0);
    const float* p001 = src + 3 * (zs0 + ys0 + x1);
    const float* p010 = src + 3 * (zs0 + ys1 + x0);
    const float* p011 = src + 3 * (zs0 + ys1 + x1);
    const float* p100 = src + 3 * (zs1 + ys0 + x0);
    const float* p101 = src + 3 * (zs1 + ys0 + x1);
    const float* p110 = src + 3 * (zs1 + ys1 + x0);
    const float* p111 = src + 3 * (zs1 + ys1 + x1);

    float w000 = omz * omy * omx, w001 = omz * omy * wx;
    float w010 = omz * wy * omx,  w011 = omz * wy * wx;
    float w100 = wz * omy * omx,  w101 = wz * omy * wx;
    float w110 = wz * wy * omx,   w111 = wz * wy * wx;

    r0 = w000 * p000[0] + w001 * p001[0] + w010 * p010[0] + w011 * p011[0]
       + w100 * p100[0] + w101 * p101[0] + w110 * p110[0] + w111 * p111[0];
    r1 = w000 * p000[1] + w001 * p001[1] + w010 * p010[1] + w011 * p011[1]
       + w100 * p100[1] + w101 * p101[1] + w110 * p110[1] + w111 * p111[1];
    r2 = w000 * p000[2] + w001 * p001[2] + w010 * p010[2] + w011 * p011[2]
       + w100 * p100[2] + w101 * p101[2] + w110 * p110[2] + w111 * p111[2];
}

// bilinear warp of a 1-channel planar volume (exact round-0 expression order)
__device__ __forceinline__ float trilerp1(const float* __restrict__ vol,
                                          float cz, float cy, float cx) {
    float z0f = floorf(cz), y0f = floorf(cy), x0f = floorf(cx);
    float wz = cz - z0f, wy = cy - y0f, wx = cx - x0f;
    int z0 = (int)z0f, y0 = (int)y0f, x0 = (int)x0f;
    int z1 = min(z0 + 1, DD - 1);
    int y1 = min(y0 + 1, DD - 1);
    int x1 = min(x0 + 1, DD - 1);
    float omz = 1.0f - wz, omy = 1.0f - wy, omx = 1.0f - wx;
    int zs0 = z0 << 14, zs1 = z1 << 14;
    int ys0 = y0 << 7,  ys1 = y1 << 7;
    return omz * omy * omx * vol[zs0 + ys0 + x0]
         + omz * omy * wx  * vol[zs0 + ys0 + x1]
         + omz * wy * omx  * vol[zs0 + ys1 + x0]
         + omz * wy * wx   * vol[zs0 + ys1 + x1]
         + wz * omy * omx  * vol[zs1 + ys0 + x0]
         + wz * omy * wx   * vol[zs1 + ys0 + x1]
         + wz * wy * omx   * vol[zs1 + ys1 + x0]
         + wz * wy * wx    * vol[zs1 + ys1 + x1];
}

// ===========================================================================
// MAIN PATH: single persistent cooperative kernel.
// 1024 blocks x 256 threads, 8 voxels/thread (x-contiguous), own
// displacements register-resident across all 7 steps, grid.sync between
// phases.  4 blocks/CU (16 waves/CU), VGPR capped at 128 by launch_bounds.
// ===========================================================================

// one squaring phase on 8 register-resident voxels: d <- d + warp-sample
__device__ __forceinline__ void gather_phase(const float* __restrict__ src,
                                             float zf, float yf, float xf0,
                                             float (&d)[24]) {
    #pragma unroll
    for (int k = 0; k < 8; ++k) {
        float cz = clampd(zf + d[3 * k + 0]);
        float cy = clampd(yf + d[3 * k + 1]);
        float cx = clampd(xf0 + (float)k + d[3 * k + 2]);
        float r0, r1, r2;
        trilerp3(src, cz, cy, cx, r0, r1, r2);
        // r += d in the verified order (commutative, bit-identical)
        d[3 * k + 0] = r0 + d[3 * k + 0];
        d[3 * k + 1] = r1 + d[3 * k + 1];
        d[3 * k + 2] = r2 + d[3 * k + 2];
    }
}

__device__ __forceinline__ void store_interleaved(float* __restrict__ dst,
                                                  int base, const float (&d)[24]) {
    float4* p = (float4*)(dst + 3 * base);   // 96B-aligned (base % 8 == 0)
    p[0] = make_float4(d[0],  d[1],  d[2],  d[3]);
    p[1] = make_float4(d[4],  d[5],  d[6],  d[7]);
    p[2] = make_float4(d[8],  d[9],  d[10], d[11]);
    p[3] = make_float4(d[12], d[13], d[14], d[15]);
    p[4] = make_float4(d[16], d[17], d[18], d[19]);
    p[5] = make_float4(d[20], d[21], d[22], d[23]);
}

__global__ __launch_bounds__(256, 4)
void coop_kernel(const float* __restrict__ dvf,
                 const float* __restrict__ mimg,
                 const float* __restrict__ mlab,
                 float* __restrict__ A,
                 float* __restrict__ B,
                 float* __restrict__ ddf_out,
                 float* __restrict__ pred_img,
                 float* __restrict__ pred_lab,
                 float* __restrict__ dvf_out) {
    cg::grid_group grid = cg::this_grid();

    int gtid = blockIdx.x * 256 + threadIdx.x;   // 262,144 threads
    int base = gtid * 8;                          // 8 x-contiguous voxels
    int x0 = base & (DD - 1);
    int y  = (base >> 7) & (DD - 1);
    int z  = base >> 14;
    float zf = (float)z, yf = (float)y, xf0 = (float)x0;

    float d[24];

    // ---- phase 0: load dvf, pass-through copy, d = dvf * 2^-7, write A ----
    {
        float4 a0 = *(const float4*)(dvf + base);
        float4 a1 = *(const float4*)(dvf + base + 4);
        float4 b0 = *(const float4*)(dvf + base + NV);
        float4 b1 = *(const float4*)(dvf + base + NV + 4);
        float4 c0 = *(const float4*)(dvf + base + 2 * NV);
        float4 c1 = *(const float4*)(dvf + base + 2 * NV + 4);

        *(float4*)(dvf_out + base)              = a0;
        *(float4*)(dvf_out + base + 4)          = a1;
        *(float4*)(dvf_out + base + NV)         = b0;
        *(float4*)(dvf_out + base + NV + 4)     = b1;
        *(float4*)(dvf_out + base + 2 * NV)     = c0;
        *(float4*)(dvf_out + base + 2 * NV + 4) = c1;

        float ch0[8] = {a0.x, a0.y, a0.z, a0.w, a1.x, a1.y, a1.z, a1.w};
        float ch1[8] = {b0.x, b0.y, b0.z, b0.w, b1.x, b1.y, b1.z, b1.w};
        float ch2[8] = {c0.x, c0.y, c0.z, c0.w, c1.x, c1.y, c1.z, c1.w};
        #pragma unroll
        for (int k = 0; k < 8; ++k) {
            d[3 * k + 0] = ch0[k] * INV_SCALE;
            d[3 * k + 1] = ch1[k] * INV_SCALE;
            d[3 * k + 2] = ch2[k] * INV_SCALE;
        }
        store_interleaved(A, base, d);
    }
    grid.sync();

    // ---- phases 1..6: ping-pong A<->B ----
    gather_phase(A, zf, yf, xf0, d);  store_interleaved(B, base, d);  grid.sync();
    gather_phase(B, zf, yf, xf0, d);  store_interleaved(A, base, d);  grid.sync();
    gather_phase(A, zf, yf, xf0, d);  store_interleaved(B, base, d);  grid.sync();
    gather_phase(B, zf, yf, xf0, d);  store_interleaved(A, base, d);  grid.sync();
    gather_phase(A, zf, yf, xf0, d);  store_interleaved(B, base, d);  grid.sync();
    gather_phase(B, zf, yf, xf0, d);  store_interleaved(A, base, d);  grid.sync();

    // ---- phase 7 + final: d becomes the ddf; write planar ddf, warp outputs
    gather_phase(A, zf, yf, xf0, d);

    // planar ddf writes (2 float4 per channel)
    *(float4*)(ddf_out + base)              = make_float4(d[0], d[3], d[6],  d[9]);
    *(float4*)(ddf_out + base + 4)          = make_float4(d[12], d[15], d[18], d[21]);
    *(float4*)(ddf_out + base + NV)         = make_float4(d[1], d[4], d[7],  d[10]);
    *(float4*)(ddf_out + base + NV + 4)     = make_float4(d[13], d[16], d[19], d[22]);
    *(float4*)(ddf_out + base + 2 * NV)     = make_float4(d[2], d[5], d[8],  d[11]);
    *(float4*)(ddf_out + base + 2 * NV + 4) = make_float4(d[14], d[17], d[20], d[23]);

    float pi[8], pl[8];
    #pragma unroll
    for (int k = 0; k < 8; ++k) {
        float fz = clampd(zf + d[3 * k + 0]);
        float fy = clampd(yf + d[3 * k + 1]);
        float fx = clampd(xf0 + (float)k + d[3 * k + 2]);
        pi[k] = trilerp1(mimg, fz, fy, fx);
        int zi = (int)rintf(fz), yi = (int)rintf(fy), xi = (int)rintf(fx);
        pl[k] = mlab[(zi << 14) + (yi << 7) + xi];
    }
    *(float4*)(pred_img + base)     = make_float4(pi[0], pi[1], pi[2], pi[3]);
    *(float4*)(pred_img + base + 4) = make_float4(pi[4], pi[5], pi[6], pi[7]);
    *(float4*)(pred_lab + base)     = make_float4(pl[0], pl[1], pl[2], pl[3]);
    *(float4*)(pred_lab + base + 4) = make_float4(pl[4], pl[5], pl[6], pl[7]);
}

// ===========================================================================
// FALLBACK 1 (coop launch failed, workspace ok): r4 pipeline (259 µs)
// ===========================================================================

__global__ __launch_bounds__(256)
void init_fused_kernel(const float* __restrict__ dvf,
                       float* __restrict__ A,
                       float* __restrict__ dvf_out) {
    int vbid = swz(blockIdx.x, 2048 / NXCD);
    int base = vbid * 1024 + threadIdx.x * 4;

    float4 a = *(const float4*)(dvf + base);
    float4 b = *(const float4*)(dvf + base + NV);
    float4 c = *(const float4*)(dvf + base + 2 * NV);

    *(float4*)(dvf_out + base)          = a;
    *(float4*)(dvf_out + base + NV)     = b;
    *(float4*)(dvf_out + base + 2 * NV) = c;

    float4 o0 = make_float4(a.x * INV_SCALE, b.x * INV_SCALE, c.x * INV_SCALE,
                            a.y * INV_SCALE);
    float4 o1 = make_float4(b.y * INV_SCALE, c.y * INV_SCALE, a.z * INV_SCALE,
                            b.z * INV_SCALE);
    float4 o2 = make_float4(c.z * INV_SCALE, a.w * INV_SCALE, b.w * INV_SCALE,
                            c.w * INV_SCALE);
    float* p = A + 3 * base;
    *(float4*)(p)     = o0;
    *(float4*)(p + 4) = o1;
    *(float4*)(p + 8) = o2;
}

__global__ __launch_bounds__(256)
void step_kernel(const float* __restrict__ src, float* __restrict__ dst) {
    int vbid = swz(blockIdx.x, 8192 / NXCD);
    int tid = vbid * 256 + threadIdx.x;
    int z, y, x;
    unpack_zyx(tid, z, y, x);

    const float* s = src + 3 * tid;
    float d0 = s[0], d1 = s[1], d2 = s[2];

    float cz = clampd((float)z + d0);
    float cy = clampd((float)y + d1);
    float cx = clampd((float)x + d2);

    float r0, r1, r2;
    trilerp3(src, cz, cy, cx, r0, r1, r2);

    r0 += d0; r1 += d1; r2 += d2;

    float* p = dst + 3 * tid;
    p[0] = r0; p[1] = r1; p[2] = r2;
}

__global__ __launch_bounds__(256)
void step7_final_kernel(const float* __restrict__ src,
                        const float* __restrict__ mimg,
                        const float* __restrict__ mlab,
                        float* __restrict__ ddf_out,
                        float* __restrict__ pred_img,
                        float* __restrict__ pred_lab) {
    int vbid = swz(blockIdx.x, 8192 / NXCD);
    int tid = vbid * 256 + threadIdx.x;
    int z, y, x;
    unpack_zyx(tid, z, y, x);

    const float* s = src + 3 * tid;
    float d0 = s[0], d1 = s[1], d2 = s[2];

    float cz = clampd((float)z + d0);
    float cy = clampd((float)y + d1);
    float cx = clampd((float)x + d2);

    float r0, r1, r2;
    trilerp3(src, cz, cy, cx, r0, r1, r2);
    r0 += d0; r1 += d1; r2 += d2;

    ddf_out[tid]          = r0;
    ddf_out[tid + NV]     = r1;
    ddf_out[tid + 2 * NV] = r2;

    float fz = clampd((float)z + r0);
    float fy = clampd((float)y + r1);
    float fx = clampd((float)x + r2);

    pred_img[tid] = trilerp1(mimg, fz, fy, fx);

    int zi = (int)rintf(fz), yi = (int)rintf(fy), xi = (int)rintf(fx);
    pred_lab[tid] = mlab[(zi << 14) + (yi << 7) + xi];
}

// ===========================================================================
// FALLBACK 2 (workspace too small): round-0 verified pipeline in d_out
// ===========================================================================

__global__ __launch_bounds__(256)
void init_kernel_fb(const float* __restrict__ dvf, float* __restrict__ A) {
    int tid = blockIdx.x * blockDim.x + threadIdx.x;
    float d0 = dvf[tid] * INV_SCALE;
    float d1 = dvf[tid + NV] * INV_SCALE;
    float d2 = dvf[tid + 2 * NV] * INV_SCALE;
    float* p = A + 3 * tid;
    p[0] = d0; p[1] = d1; p[2] = d2;
}

template <bool PLANAR_OUT>
__global__ __launch_bounds__(256)
void step_kernel_fb(const float* __restrict__ src, float* __restrict__ dst) {
    int tid = blockIdx.x * blockDim.x + threadIdx.x;
    int z, y, x;
    unpack_zyx(tid, z, y, x);
    const float* s = src + 3 * tid;
    float d0 = s[0], d1 = s[1], d2 = s[2];
    float cz = clampd((float)z + d0);
    float cy = clampd((float)y + d1);
    float cx = clampd((float)x + d2);
    float r0, r1, r2;
    trilerp3(src, cz, cy, cx, r0, r1, r2);
    r0 += d0; r1 += d1; r2 += d2;
    if (PLANAR_OUT) {
        dst[tid]          = r0;
        dst[tid + NV]     = r1;
        dst[tid + 2 * NV] = r2;
    } else {
        float* p = dst + 3 * tid;
        p[0] = r0; p[1] = r1; p[2] = r2;
    }
}

__global__ __launch_bounds__(256)
void final_kernel_fb(const float* __restrict__ ddf,
                     const float* __restrict__ mimg,
                     const float* __restrict__ mlab,
                     const float* __restrict__ dvf,
                     float* __restrict__ pred_img,
                     float* __restrict__ pred_lab,
                     float* __restrict__ dvf_out) {
    int tid = blockIdx.x * blockDim.x + threadIdx.x;
    int z, y, x;
    unpack_zyx(tid, z, y, x);
    float d0 = ddf[tid];
    float d1 = ddf[tid + NV];
    float d2 = ddf[tid + 2 * NV];
    float cz = clampd((float)z + d0);
    float cy = clampd((float)y + d1);
    float cx = clampd((float)x + d2);
    pred_img[tid] = trilerp1(mimg, cz, cy, cx);
    int zi = (int)rintf(cz);
    int yi = (int)rintf(cy);
    int xi = (int)rintf(cx);
    pred_lab[tid] = mlab[(zi << 14) + (yi << 7) + xi];
    dvf_out[tid]          = dvf[tid];
    dvf_out[tid + NV]     = dvf[tid + NV];
    dvf_out[tid + 2 * NV] = dvf[tid + 2 * NV];
}

// ===========================================================================

extern "C" void kernel_launch(void* const* d_in, const int* in_sizes, int n_in,
                              void* d_out, int out_size, void* d_ws, size_t ws_size,
                              hipStream_t stream) {
    const float* dvf  = (const float*)d_in[0];
    const float* mimg = (const float*)d_in[1];
    // d_in[2] = fixed_image: unused by the reference outputs
    const float* mlab = (const float*)d_in[3];

    float* out      = (float*)d_out;
    float* ddf_out  = out;              // slot 0: ddf  [3,D,H,W]
    float* pred_img = out + 3 * NV;     // slot 1
    float* pred_lab = out + 4 * NV;     // slot 2
    float* dvf_out  = out + 5 * NV;     // slot 3: dvf pass-through

    dim3 block(256);
    dim3 grid(NV / 256);       // 8192 blocks (fallback steps)
    dim3 igrid(NV / 1024);     // 2048 blocks (fallback init)

    size_t need = (size_t)2 * NV * 3 * sizeof(float);  // 48 MiB ping-pong
    if (d_ws != nullptr && ws_size >= need) {
        float* A = (float*)d_ws;          // interleaved 12B
        float* B = A + (size_t)3 * NV;

        const float* dvf_p  = dvf;
        const float* mimg_p = mimg;
        const float* mlab_p = mlab;
        float* A_p = A;
        float* B_p = B;
        float* ddf_p = ddf_out;
        float* img_p = pred_img;
        float* lab_p = pred_lab;
        float* dvo_p = dvf_out;
        void* args[] = {(void*)&dvf_p, (void*)&mimg_p, (void*)&mlab_p,
                        (void*)&A_p, (void*)&B_p, (void*)&ddf_p,
                        (void*)&img_p, (void*)&lab_p, (void*)&dvo_p};

        hipError_t e = hipLaunchCooperativeKernel(
            reinterpret_cast<void*>(coop_kernel),
            dim3(1024), dim3(256), args, 0, stream);

        if (e != hipSuccess) {
            // fallback 1: r4 measured pipeline (259 µs)
            init_fused_kernel<<<igrid, block, 0, stream>>>(dvf, A, dvf_out);
            step_kernel<<<grid, block, 0, stream>>>(A, B);  // 1
            step_kernel<<<grid, block, 0, stream>>>(B, A);  // 2
            step_kernel<<<grid, block, 0, stream>>>(A, B);  // 3
            step_kernel<<<grid, block, 0, stream>>>(B, A);  // 4
            step_kernel<<<grid, block, 0, stream>>>(A, B);  // 5
            step_kernel<<<grid, block, 0, stream>>>(B, A);  // 6
            step7_final_kernel<<<grid, block, 0, stream>>>(A, mimg, mlab,
                                                           ddf_out, pred_img,
                                                           pred_lab);     // 7
        }
    } else {
        // fallback 2: round-0 verified pipeline (scratch inside d_out)
        float* A = dvf_out;
        float* B = ddf_out;
        init_kernel_fb<<<grid, block, 0, stream>>>(dvf, A);
        step_kernel_fb<false><<<grid, block, 0, stream>>>(A, B);  // 1
        step_kernel_fb<false><<<grid, block, 0, stream>>>(B, A);  // 2
        step_kernel_fb<false><<<grid, block, 0, stream>>>(A, B);  // 3
        step_kernel_fb<false><<<grid, block, 0, stream>>>(B, A);  // 4
        step_kernel_fb<false><<<grid, block, 0, stream>>>(A, B);  // 5
        step_kernel_fb<false><<<grid, block, 0, stream>>>(B, A);  // 6
        step_kernel_fb<true ><<<grid, block, 0, stream>>>(A, B);  // 7
        final_kernel_fb<<<grid, block, 0, stream>>>(B, mimg, mlab, dvf,
                                                    pred_img, pred_lab, dvf_out);
    }
}

// Round 7
// 260.064 us; speedup vs baseline: 6.9084x; 6.9084x over previous
//
#include <hip/hip_runtime.h>

// D = H = W = 128, NUM_STEPS = 7 (MONAI DVF2DDF scaling-and-squaring)
#define DD 128
constexpr int NV = DD * DD * DD;          // 2,097,152 voxels
constexpr float INV_SCALE = 1.0f / 128.0f; // 2^-NUM_STEPS
#define NXCD 8

// consistent bijective block swizzle (perf-neutral, measured r4; kept so the
// producer/consumer block->XCD mapping stays stable across dispatches)
__device__ __forceinline__ int swz(int b, int cpx) {
    return (b & (NXCD - 1)) * cpx + (b >> 3);
}

__device__ __forceinline__ void unpack_zyx(int tid, int& z, int& y, int& x) {
    x = tid & (DD - 1);
    y = (tid >> 7) & (DD - 1);
    z = tid >> 14;
}

__device__ __forceinline__ float clampd(float v) {
    return fminf(fmaxf(v, 0.0f), (float)(DD - 1));
}

// ---------------------------------------------------------------------------
// trilinear sample of interleaved 3-channel field (EXACT round-0 expression
// order — verified bit-stable, absmax 0.00390625)
// ---------------------------------------------------------------------------
__device__ __forceinline__ void trilerp3(const float* __restrict__ src,
                                         float cz, float cy, float cx,
                                         float& r0, float& r1, float& r2) {
    float z0f = floorf(cz), y0f = floorf(cy), x0f = floorf(cx);
    float wz = cz - z0f, wy = cy - y0f, wx = cx - x0f;
    int z0 = (int)z0f, y0 = (int)y0f, x0 = (int)x0f;
    int z1 = min(z0 + 1, DD - 1);
    int y1 = min(y0 + 1, DD - 1);
    int x1 = min(x0 + 1, DD - 1);
    float omz = 1.0f - wz, omy = 1.0f - wy, omx = 1.0f - wx;

    int zs0 = z0 << 14, zs1 = z1 << 14;
    int ys0 = y0 << 7,  ys1 = y1 << 7;

    const float* p000 = src + 3 * (zs0 + ys0 + x0);
    const float* p001 = src + 3 * (zs0 + ys0 + x1);
    const float* p010 = src + 3 * (zs0 + ys1 + x0);
    const float* p011 = src + 3 * (zs0 + ys1 + x1);
    const float* p100 = src + 3 * (zs1 + ys0 + x0);
    const float* p101 = src + 3 * (zs1 + ys0 + x1);
    const float* p110 = src + 3 * (zs1 + ys1 + x0);
    const float* p111 = src + 3 * (zs1 + ys1 + x1);

    float w000 = omz * omy * omx, w001 = omz * omy * wx;
    float w010 = omz * wy * omx,  w011 = omz * wy * wx;
    float w100 = wz * omy * omx,  w101 = wz * omy * wx;
    float w110 = wz * wy * omx,   w111 = wz * wy * wx;

    r0 = w000 * p000[0] + w001 * p001[0] + w010 * p010[0] + w011 * p011[0]
       + w100 * p100[0] + w101 * p101[0] + w110 * p110[0] + w111 * p111[0];
    r1 = w000 * p000[1] + w001 * p001[1] + w010 * p010[1] + w011 * p011[1]
       + w100 * p100[1] + w101 * p101[1] + w110 * p110[1] + w111 * p111[1];
    r2 = w000 * p000[2] + w001 * p001[2] + w010 * p010[2] + w011 * p011[2]
       + w100 * p100[2] + w101 * p101[2] + w110 * p110[2] + w111 * p111[2];
}

// bilinear warp of a 1-channel planar volume (exact round-0 expression order)
__device__ __forceinline__ float trilerp1(const float* __restrict__ vol,
                                          float cz, float cy, float cx) {
    float z0f = floorf(cz), y0f = floorf(cy), x0f = floorf(cx);
    float wz = cz - z0f, wy = cy - y0f, wx = cx - x0f;
    int z0 = (int)z0f, y0 = (int)y0f, x0 = (int)x0f;
    int z1 = min(z0 + 1, DD - 1);
    int y1 = min(y0 + 1, DD - 1);
    int x1 = min(x0 + 1, DD - 1);
    float omz = 1.0f - wz, omy = 1.0f - wy, omx = 1.0f - wx;
    int zs0 = z0 << 14, zs1 = z1 << 14;
    int ys0 = y0 << 7,  ys1 = y1 << 7;
    return omz * omy * omx * vol[zs0 + ys0 + x0]
         + omz * omy * wx  * vol[zs0 + ys0 + x1]
         + omz * wy * omx  * vol[zs0 + ys1 + x0]
         + omz * wy * wx   * vol[zs0 + ys1 + x1]
         + wz * omy * omx  * vol[zs1 + ys0 + x0]
         + wz * omy * wx   * vol[zs1 + ys0 + x1]
         + wz * wy * omx   * vol[zs1 + ys1 + x0]
         + wz * wy * wx    * vol[zs1 + ys1 + x1];
}

// ===========================================================================
// MAIN PATH: 7 dispatches.
//   1: init+step1 fused (gathers raw planar dvf, scales 2^-7 after — bit
//      exact; also does dvf pass-through copy)  [measured 44.7 µs in r1]
//   2-6: interleaved squaring steps              [~32 µs each]
//   7: step7 + final warps fused                 [~42 µs]
// ===========================================================================

// ---------------------------------------------------------------------------
// fused init + step 1 + dvf pass-through:
//   reads planar dvf once; writes dvf copy to out slot 3;
//   ddf1 = s*v + s*warp_raw(v, s*v)  (s = 2^-7 exact exponent shift)
// ---------------------------------------------------------------------------
__global__ __launch_bounds__(256)
void init_step1_kernel(const float* __restrict__ dvf,
                       float* __restrict__ dst,
                       float* __restrict__ dvf_out) {
    int vbid = swz(blockIdx.x, 8192 / NXCD);
    int tid = vbid * 256 + threadIdx.x;
    int z, y, x;
    unpack_zyx(tid, z, y, x);

    float v0 = dvf[tid];
    float v1 = dvf[tid + NV];
    float v2 = dvf[tid + 2 * NV];

    // pass-through (out slot 3 is free from the start in this path)
    dvf_out[tid]          = v0;
    dvf_out[tid + NV]     = v1;
    dvf_out[tid + 2 * NV] = v2;

    float d0 = v0 * INV_SCALE, d1 = v1 * INV_SCALE, d2 = v2 * INV_SCALE;

    float cz = clampd((float)z + d0);
    float cy = clampd((float)y + d1);
    float cx = clampd((float)x + d2);

    // corners + weights (same expression order as trilerp3)
    float z0f = floorf(cz), y0f = floorf(cy), x0f = floorf(cx);
    float wz = cz - z0f, wy = cy - y0f, wx = cx - x0f;
    int z0 = (int)z0f, y0 = (int)y0f, x0 = (int)x0f;
    int z1 = min(z0 + 1, DD - 1);
    int y1 = min(y0 + 1, DD - 1);
    int x1 = min(x0 + 1, DD - 1);
    float omz = 1.0f - wz, omy = 1.0f - wy, omx = 1.0f - wx;
    int zs0 = z0 << 14, zs1 = z1 << 14;
    int ys0 = y0 << 7,  ys1 = y1 << 7;
    int i000 = zs0 + ys0 + x0, i001 = zs0 + ys0 + x1;
    int i010 = zs0 + ys1 + x0, i011 = zs0 + ys1 + x1;
    int i100 = zs1 + ys0 + x0, i101 = zs1 + ys0 + x1;
    int i110 = zs1 + ys1 + x0, i111 = zs1 + ys1 + x1;

    float w000 = omz * omy * omx, w001 = omz * omy * wx;
    float w010 = omz * wy * omx,  w011 = omz * wy * wx;
    float w100 = wz * omy * omx,  w101 = wz * omy * wx;
    float w110 = wz * wy * omx,   w111 = wz * wy * wx;

    const float* ch0 = dvf;
    const float* ch1 = dvf + NV;
    const float* ch2 = dvf + 2 * NV;

    float t0 = w000 * ch0[i000] + w001 * ch0[i001]
             + w010 * ch0[i010] + w011 * ch0[i011]
             + w100 * ch0[i100] + w101 * ch0[i101]
             + w110 * ch0[i110] + w111 * ch0[i111];
    float t1 = w000 * ch1[i000] + w001 * ch1[i001]
             + w010 * ch1[i010] + w011 * ch1[i011]
             + w100 * ch1[i100] + w101 * ch1[i101]
             + w110 * ch1[i110] + w111 * ch1[i111];
    float t2 = w000 * ch2[i000] + w001 * ch2[i001]
             + w010 * ch2[i010] + w011 * ch2[i011]
             + w100 * ch2[i100] + w101 * ch2[i101]
             + w110 * ch2[i110] + w111 * ch2[i111];

    float* p = dst + 3 * tid;
    p[0] = t0 * INV_SCALE + d0;
    p[1] = t1 * INV_SCALE + d1;
    p[2] = t2 * INV_SCALE + d2;
}

// ---------------------------------------------------------------------------
// squaring step (steps 2..6): dst = src + warp(src, src), interleaved 12B.
// ---------------------------------------------------------------------------
__global__ __launch_bounds__(256)
void step_kernel(const float* __restrict__ src, float* __restrict__ dst) {
    int vbid = swz(blockIdx.x, 8192 / NXCD);
    int tid = vbid * 256 + threadIdx.x;
    int z, y, x;
    unpack_zyx(tid, z, y, x);

    const float* s = src + 3 * tid;
    float d0 = s[0], d1 = s[1], d2 = s[2];

    float cz = clampd((float)z + d0);
    float cy = clampd((float)y + d1);
    float cx = clampd((float)x + d2);

    float r0, r1, r2;
    trilerp3(src, cz, cy, cx, r0, r1, r2);

    r0 += d0; r1 += d1; r2 += d2;

    float* p = dst + 3 * tid;
    p[0] = r0; p[1] = r1; p[2] = r2;
}

// ---------------------------------------------------------------------------
// fused step 7 + final: computes ddf in registers, writes planar ddf, then
// immediately warps moving_image (bilinear) and moving_label (nearest) with
// the register ddf (bit-identical to store-then-reload).
// ---------------------------------------------------------------------------
__global__ __launch_bounds__(256)
void step7_final_kernel(const float* __restrict__ src,
                        const float* __restrict__ mimg,
                        const float* __restrict__ mlab,
                        float* __restrict__ ddf_out,
                        float* __restrict__ pred_img,
                        float* __restrict__ pred_lab) {
    int vbid = swz(blockIdx.x, 8192 / NXCD);
    int tid = vbid * 256 + threadIdx.x;
    int z, y, x;
    unpack_zyx(tid, z, y, x);

    const float* s = src + 3 * tid;
    float d0 = s[0], d1 = s[1], d2 = s[2];

    float cz = clampd((float)z + d0);
    float cy = clampd((float)y + d1);
    float cx = clampd((float)x + d2);

    float r0, r1, r2;
    trilerp3(src, cz, cy, cx, r0, r1, r2);
    r0 += d0; r1 += d1; r2 += d2;

    ddf_out[tid]          = r0;
    ddf_out[tid + NV]     = r1;
    ddf_out[tid + 2 * NV] = r2;

    float fz = clampd((float)z + r0);
    float fy = clampd((float)y + r1);
    float fx = clampd((float)x + r2);

    pred_img[tid] = trilerp1(mimg, fz, fy, fx);

    int zi = (int)rintf(fz), yi = (int)rintf(fy), xi = (int)rintf(fx);
    pred_lab[tid] = mlab[(zi << 14) + (yi << 7) + xi];
}

// ===========================================================================
// FALLBACK PATH (workspace too small): round-0 verified pipeline in d_out
// ===========================================================================

__global__ __launch_bounds__(256)
void init_kernel_fb(const float* __restrict__ dvf, float* __restrict__ A) {
    int tid = blockIdx.x * blockDim.x + threadIdx.x;
    float d0 = dvf[tid] * INV_SCALE;
    float d1 = dvf[tid + NV] * INV_SCALE;
    float d2 = dvf[tid + 2 * NV] * INV_SCALE;
    float* p = A + 3 * tid;
    p[0] = d0; p[1] = d1; p[2] = d2;
}

template <bool PLANAR_OUT>
__global__ __launch_bounds__(256)
void step_kernel_fb(const float* __restrict__ src, float* __restrict__ dst) {
    int tid = blockIdx.x * blockDim.x + threadIdx.x;
    int z, y, x;
    unpack_zyx(tid, z, y, x);
    const float* s = src + 3 * tid;
    float d0 = s[0], d1 = s[1], d2 = s[2];
    float cz = clampd((float)z + d0);
    float cy = clampd((float)y + d1);
    float cx = clampd((float)x + d2);
    float r0, r1, r2;
    trilerp3(src, cz, cy, cx, r0, r1, r2);
    r0 += d0; r1 += d1; r2 += d2;
    if (PLANAR_OUT) {
        dst[tid]          = r0;
        dst[tid + NV]     = r1;
        dst[tid + 2 * NV] = r2;
    } else {
        float* p = dst + 3 * tid;
        p[0] = r0; p[1] = r1; p[2] = r2;
    }
}

__global__ __launch_bounds__(256)
void final_kernel_fb(const float* __restrict__ ddf,
                     const float* __restrict__ mimg,
                     const float* __restrict__ mlab,
                     const float* __restrict__ dvf,
                     float* __restrict__ pred_img,
                     float* __restrict__ pred_lab,
                     float* __restrict__ dvf_out) {
    int tid = blockIdx.x * blockDim.x + threadIdx.x;
    int z, y, x;
    unpack_zyx(tid, z, y, x);
    float d0 = ddf[tid];
    float d1 = ddf[tid + NV];
    float d2 = ddf[tid + 2 * NV];
    float cz = clampd((float)z + d0);
    float cy = clampd((float)y + d1);
    float cx = clampd((float)x + d2);
    pred_img[tid] = trilerp1(mimg, cz, cy, cx);
    int zi = (int)rintf(cz);
    int yi = (int)rintf(cy);
    int xi = (int)rintf(cx);
    pred_lab[tid] = mlab[(zi << 14) + (yi << 7) + xi];
    dvf_out[tid]          = dvf[tid];
    dvf_out[tid + NV]     = dvf[tid + NV];
    dvf_out[tid + 2 * NV] = dvf[tid + 2 * NV];
}

// ===========================================================================

extern "C" void kernel_launch(void* const* d_in, const int* in_sizes, int n_in,
                              void* d_out, int out_size, void* d_ws, size_t ws_size,
                              hipStream_t stream) {
    const float* dvf  = (const float*)d_in[0];
    const float* mimg = (const float*)d_in[1];
    // d_in[2] = fixed_image: unused by the reference outputs
    const float* mlab = (const float*)d_in[3];

    float* out      = (float*)d_out;
    float* ddf_out  = out;              // slot 0: ddf  [3,D,H,W]
    float* pred_img = out + 3 * NV;     // slot 1
    float* pred_lab = out + 4 * NV;     // slot 2
    float* dvf_out  = out + 5 * NV;     // slot 3: dvf pass-through

    dim3 block(256);
    dim3 grid(NV / 256);       // 8192 blocks

    size_t need = (size_t)2 * NV * 3 * sizeof(float);  // 48 MiB ping-pong
    if (d_ws != nullptr && ws_size >= need) {
        float* A = (float*)d_ws;          // interleaved 12B
        float* B = A + (size_t)3 * NV;
        // step 1 fused with init + dvf pass-through -> A
        init_step1_kernel<<<grid, block, 0, stream>>>(dvf, A, dvf_out);
        step_kernel<<<grid, block, 0, stream>>>(A, B);  // 2
        step_kernel<<<grid, block, 0, stream>>>(B, A);  // 3
        step_kernel<<<grid, block, 0, stream>>>(A, B);  // 4
        step_kernel<<<grid, block, 0, stream>>>(B, A);  // 5
        step_kernel<<<grid, block, 0, stream>>>(A, B);  // 6
        step7_final_kernel<<<grid, block, 0, stream>>>(B, mimg, mlab,
                                                       ddf_out, pred_img,
                                                       pred_lab);         // 7
    } else {
        // fallback: round-0 verified pipeline (scratch inside d_out)
        float* A = dvf_out;
        float* B = ddf_out;
        init_kernel_fb<<<grid, block, 0, stream>>>(dvf, A);
        step_kernel_fb<false><<<grid, block, 0, stream>>>(A, B);  // 1
        step_kernel_fb<false><<<grid, block, 0, stream>>>(B, A);  // 2
        step_kernel_fb<false><<<grid, block, 0, stream>>>(A, B);  // 3
        step_kernel_fb<false><<<grid, block, 0, stream>>>(B, A);  // 4
        step_kernel_fb<false><<<grid, block, 0, stream>>>(A, B);  // 5
        step_kernel_fb<false><<<grid, block, 0, stream>>>(B, A);  // 6
        step_kernel_fb<true ><<<grid, block, 0, stream>>>(A, B);  // 7
        final_kernel_fb<<<grid, block, 0, stream>>>(B, mimg, mlab, dvf,
                                                    pred_img, pred_lab, dvf_out);
    }
}